// Round 1
// baseline (1958.554 us; speedup 1.0000x reference)
//
#include <hip/hip_runtime.h>
#include <hip/hip_bf16.h>
#include <cstdint>

// Problem constants (from reference)
#define TT     2048   // tokens
#define KSEL   6      // experts per token
#define DMODEL 2048   // model dim
#define DINTER 1408   // moe intermediate dim
#define NE     16     // routed experts
#define PMAX   (TT * KSEL)

typedef short bf16x8 __attribute__((ext_vector_type(8)));
typedef float f32x4 __attribute__((ext_vector_type(4)));
typedef unsigned short u16;
typedef u16 u16x8 __attribute__((ext_vector_type(8)));

__device__ __forceinline__ u16 f2bf(float f) {
  union { float f; unsigned u; } v; v.f = f;
  return (u16)((v.u + 0x7FFFu + ((v.u >> 16) & 1u)) >> 16);  // RNE
}

__device__ __forceinline__ void gl2lds16(const void* g, void* l) {
  __builtin_amdgcn_global_load_lds((const __attribute__((address_space(1))) void*)g,
                                   (__attribute__((address_space(3))) void*)l,
                                   16, 0, 0);
}

// gate_w[t,e] = sum_k weights[t,k]*(indices[t,k]==e); count routed (t,e) pairs
__global__ void k_gate(const float* __restrict__ w, const int* __restrict__ idx,
                       float* __restrict__ gate_w, int* __restrict__ counts) {
  int g = blockIdx.x * 256 + threadIdx.x;  // T*E threads
  int t = g >> 4, e = g & 15;
  const int* ip = idx + t * KSEL;
  const float* wp = w + t * KSEL;
  float s = 0.f;
#pragma unroll
  for (int k = 0; k < KSEL; ++k) s += (ip[k] == e) ? wp[k] : 0.f;
  gate_w[g] = s;
  if (s != 0.f) atomicAdd(counts + e, 1);
}

__global__ void k_scan(const int* __restrict__ counts, int* __restrict__ offs) {
  if (threadIdx.x == 0 && blockIdx.x == 0) {
    int r = 0;
#pragma unroll
    for (int e = 0; e < NE; ++e) { offs[e] = r; r += counts[e]; }
    offs[NE] = r;
  }
}

__global__ void k_fill(const float* __restrict__ gate_w, const int* __restrict__ offs,
                       int* __restrict__ cursor, int* __restrict__ slot_tok,
                       float* __restrict__ slot_gate) {
  int g = blockIdx.x * 256 + threadIdx.x;
  int t = g >> 4, e = g & 15;
  float s = gate_w[g];
  if (s != 0.f) {
    int p = atomicAdd(cursor + e, 1);
    int sl = offs[e] + p;
    slot_tok[sl] = t;
    slot_gate[sl] = s;
  }
}

__global__ void k_castx(const float* __restrict__ x, u16* __restrict__ xb) {
  int i = blockIdx.x * 256 + threadIdx.x;  // 8 elems per thread
  const float4* p = (const float4*)x + (size_t)i * 2;
  float4 v0 = p[0], v1 = p[1];
  u16x8 o;
  o[0] = f2bf(v0.x); o[1] = f2bf(v0.y); o[2] = f2bf(v0.z); o[3] = f2bf(v0.w);
  o[4] = f2bf(v1.x); o[5] = f2bf(v1.y); o[6] = f2bf(v1.z); o[7] = f2bf(v1.w);
  *(u16x8*)(xb + (size_t)i * 8) = o;
}

// GEMM1: act[slot, i] = silu(x@WgT)*(x@WuT)*gate, per expert token-group.
// 128(M tokens) x 128(N inter) tile, BK=64, 4 waves each 64x64, dual acc (g,u).
__global__ __launch_bounds__(256, 2) void k_gemm1(
    const u16* __restrict__ xb, const float* __restrict__ Wg, const float* __restrict__ Wu,
    const int* __restrict__ slot_tok, const float* __restrict__ slot_gate,
    const int* __restrict__ offs, const int* __restrict__ counts,
    u16* __restrict__ act) {
  int e = blockIdx.z;
  int mcount = counts[e];
  int mt = blockIdx.x;
  if (mt * 128 >= mcount) return;
  int mrem = mcount - mt * 128; if (mrem > 128) mrem = 128;
  int slotBase = offs[e] + mt * 128;
  int iBase = blockIdx.y * 128;

  __shared__ u16 sA[128 * 64];
  __shared__ u16 sG[128 * 64];
  __shared__ u16 sU[128 * 64];
  __shared__ int tokLds[128];
  __shared__ float gateLds[128];

  int tid = threadIdx.x;
  if (tid < 128) {
    int rl = tid < mrem ? tid : 0;        // pad rows clamp to row 0 (valid addr)
    tokLds[tid] = slot_tok[slotBase + rl];
    gateLds[tid] = (tid < mrem) ? slot_gate[slotBase + rl] : 0.f;
  }
  __syncthreads();

  int wv = tid >> 6, lane = tid & 63;
  // A staging: 16 chunks of 1KB; wave-uniform LDS base, per-lane gathered global src
  const u16* aSrc[4]; u16* aDst[4];
#pragma unroll
  for (int i2 = 0; i2 < 4; ++i2) {
    int chunk = wv * 4 + i2;
    int row = chunk * 8 + (lane >> 3);
    aSrc[i2] = xb + (size_t)tokLds[row] * DMODEL + (lane & 7) * 8;
    aDst[i2] = sA + chunk * 512;
  }
  const float* gBase = Wg + ((size_t)e * DINTER + iBase) * DMODEL;
  const float* uBase = Wu + ((size_t)e * DINTER + iBase) * DMODEL;

  f32x4 accg[4][4] = {};
  f32x4 accu[4][4] = {};
  int fr = lane & 15, fq = lane >> 4;
  int wr = (wv >> 1) * 64, wc = (wv & 1) * 64;

  for (int kb = 0; kb < DMODEL / 64; ++kb) {
    int kOff = kb * 64;
    __syncthreads();
#pragma unroll
    for (int i2 = 0; i2 < 4; ++i2) gl2lds16(aSrc[i2] + kOff, aDst[i2]);
    // B tiles: fp32 -> bf16 reg-staged (weights read exactly once from HBM per tile pass)
#pragma unroll
    for (int j = 0; j < 8; ++j) {
      int f = j * 256 + tid;
      int row = f >> 4, c4 = f & 15;
      float4 v = *(const float4*)(gBase + (size_t)row * DMODEL + kOff + c4 * 4);
      ushort4 h; h.x = f2bf(v.x); h.y = f2bf(v.y); h.z = f2bf(v.z); h.w = f2bf(v.w);
      *(ushort4*)&sG[row * 64 + c4 * 4] = h;
    }
#pragma unroll
    for (int j = 0; j < 8; ++j) {
      int f = j * 256 + tid;
      int row = f >> 4, c4 = f & 15;
      float4 v = *(const float4*)(uBase + (size_t)row * DMODEL + kOff + c4 * 4);
      ushort4 h; h.x = f2bf(v.x); h.y = f2bf(v.y); h.z = f2bf(v.z); h.w = f2bf(v.w);
      *(ushort4*)&sU[row * 64 + c4 * 4] = h;
    }
    __syncthreads();
#pragma unroll
    for (int kf = 0; kf < 2; ++kf) {
      bf16x8 af[4], bg[4], bu[4];
#pragma unroll
      for (int mf = 0; mf < 4; ++mf)
        af[mf] = *(const bf16x8*)&sA[(wr + mf * 16 + fr) * 64 + kf * 32 + fq * 8];
#pragma unroll
      for (int nf = 0; nf < 4; ++nf) {
        bg[nf] = *(const bf16x8*)&sG[(wc + nf * 16 + fr) * 64 + kf * 32 + fq * 8];
        bu[nf] = *(const bf16x8*)&sU[(wc + nf * 16 + fr) * 64 + kf * 32 + fq * 8];
      }
#pragma unroll
      for (int mf = 0; mf < 4; ++mf)
#pragma unroll
        for (int nf = 0; nf < 4; ++nf) {
          accg[mf][nf] = __builtin_amdgcn_mfma_f32_16x16x32_bf16(af[mf], bg[nf], accg[mf][nf], 0, 0, 0);
          accu[mf][nf] = __builtin_amdgcn_mfma_f32_16x16x32_bf16(af[mf], bu[nf], accu[mf][nf], 0, 0, 0);
        }
    }
  }
  // epilogue: act = silu(g)*u*gate -> bf16  (D layout: col=lane&15, row=(lane>>4)*4+r)
#pragma unroll
  for (int mf = 0; mf < 4; ++mf)
#pragma unroll
    for (int nf = 0; nf < 4; ++nf)
#pragma unroll
      for (int r = 0; r < 4; ++r) {
        int row = wr + mf * 16 + fq * 4 + r;
        if (row < mrem) {
          float g = accg[mf][nf][r], u = accu[mf][nf][r];
          float a = g / (1.f + __expf(-g)) * u * gateLds[row];
          act[(size_t)(slotBase + row) * DINTER + iBase + wc + nf * 16 + fr] = f2bf(a);
        }
      }
}

// GEMM2: y[tok, d] += act[slot,:] @ Wd[e,d,:]  (atomic scatter, <=6 adds/elem)
__global__ __launch_bounds__(256, 2) void k_gemm2(
    const u16* __restrict__ act, const float* __restrict__ Wd,
    const int* __restrict__ slot_tok, const int* __restrict__ offs,
    const int* __restrict__ counts, float* __restrict__ y) {
  int e = blockIdx.z;
  int mcount = counts[e];
  int mt = blockIdx.x;
  if (mt * 128 >= mcount) return;
  int mrem = mcount - mt * 128; if (mrem > 128) mrem = 128;
  int slotBase = offs[e] + mt * 128;
  int dBase = blockIdx.y * 128;

  __shared__ u16 sA[128 * 64];
  __shared__ u16 sB[128 * 64];
  __shared__ int tokLds[128];

  int tid = threadIdx.x;
  if (tid < 128) tokLds[tid] = slot_tok[slotBase + (tid < mrem ? tid : 0)];
  __syncthreads();

  int wv = tid >> 6, lane = tid & 63;
  const u16* aSrc[4]; u16* aDst[4];
#pragma unroll
  for (int i2 = 0; i2 < 4; ++i2) {
    int chunk = wv * 4 + i2;
    int row = chunk * 8 + (lane >> 3);
    aSrc[i2] = act + (size_t)(slotBase + row) * DINTER + (lane & 7) * 8;  // act padded +128 rows
    aDst[i2] = sA + chunk * 512;
  }
  const float* bBase = Wd + ((size_t)e * DMODEL + dBase) * DINTER;

  f32x4 acc[4][4] = {};
  int fr = lane & 15, fq = lane >> 4;
  int wr = (wv >> 1) * 64, wc = (wv & 1) * 64;

  for (int kb = 0; kb < DINTER / 64; ++kb) {
    int kOff = kb * 64;
    __syncthreads();
#pragma unroll
    for (int i2 = 0; i2 < 4; ++i2) gl2lds16(aSrc[i2] + kOff, aDst[i2]);
#pragma unroll
    for (int j = 0; j < 8; ++j) {
      int f = j * 256 + tid;
      int row = f >> 4, c4 = f & 15;
      float4 v = *(const float4*)(bBase + (size_t)row * DINTER + kOff + c4 * 4);
      ushort4 h; h.x = f2bf(v.x); h.y = f2bf(v.y); h.z = f2bf(v.z); h.w = f2bf(v.w);
      *(ushort4*)&sB[row * 64 + c4 * 4] = h;
    }
    __syncthreads();
#pragma unroll
    for (int kf = 0; kf < 2; ++kf) {
      bf16x8 af[4], bb[4];
#pragma unroll
      for (int mf = 0; mf < 4; ++mf)
        af[mf] = *(const bf16x8*)&sA[(wr + mf * 16 + fr) * 64 + kf * 32 + fq * 8];
#pragma unroll
      for (int nf = 0; nf < 4; ++nf)
        bb[nf] = *(const bf16x8*)&sB[(wc + nf * 16 + fr) * 64 + kf * 32 + fq * 8];
#pragma unroll
      for (int mf = 0; mf < 4; ++mf)
#pragma unroll
        for (int nf = 0; nf < 4; ++nf)
          acc[mf][nf] = __builtin_amdgcn_mfma_f32_16x16x32_bf16(af[mf], bb[nf], acc[mf][nf], 0, 0, 0);
    }
  }
#pragma unroll
  for (int mf = 0; mf < 4; ++mf)
#pragma unroll
    for (int nf = 0; nf < 4; ++nf)
#pragma unroll
      for (int r = 0; r < 4; ++r) {
        int row = wr + mf * 16 + fq * 4 + r;
        if (row < mrem) {
          int t = tokLds[row];
          atomicAdd(y + (size_t)t * DMODEL + dBase + wc + nf * 16 + fr, acc[mf][nf][r]);
        }
      }
}

extern "C" void kernel_launch(void* const* d_in, const int* in_sizes, int n_in,
                              void* d_out, int out_size, void* d_ws, size_t ws_size,
                              hipStream_t stream) {
  const float* x       = (const float*)d_in[0];
  const float* weights = (const float*)d_in[1];
  const int*   indices = (const int*)d_in[2];
  const float* Wg      = (const float*)d_in[3];
  const float* Wu      = (const float*)d_in[4];
  const float* Wd      = (const float*)d_in[5];
  float* y = (float*)d_out;

  char* ws = (char*)d_ws;
  size_t o = 0;
  float* gate_w = (float*)(ws + o); o += (size_t)TT * NE * 4;       // 131072
  size_t ctrlOff = o;
  int* counts = (int*)(ws + o);
  int* offs   = (int*)(ws + o + 64);
  int* cursor = (int*)(ws + o + 192);
  o += 256;
  int*   slot_tok  = (int*)(ws + o);   o += (size_t)PMAX * 4;
  float* slot_gate = (float*)(ws + o); o += (size_t)PMAX * 4;
  u16* xb  = (u16*)(ws + o); o += (size_t)TT * DMODEL * 2;
  u16* act = (u16*)(ws + o); o += (size_t)(PMAX + 128) * DINTER * 2; // +128 pad rows
  (void)ws_size; (void)in_sizes; (void)n_in;

  hipMemsetAsync(d_out, 0, (size_t)out_size * 4, stream);
  hipMemsetAsync(ws + ctrlOff, 0, 256, stream);

  k_gate<<<TT * NE / 256, 256, 0, stream>>>(weights, indices, gate_w, counts);
  k_scan<<<1, 64, 0, stream>>>(counts, offs);
  k_fill<<<TT * NE / 256, 256, 0, stream>>>(gate_w, offs, cursor, slot_tok, slot_gate);
  k_castx<<<(TT * DMODEL / 8) / 256, 256, 0, stream>>>(x, xb);
  k_gemm1<<<dim3(16, DINTER / 128, NE), 256, 0, stream>>>(xb, Wg, Wu, slot_tok, slot_gate,
                                                          offs, counts, act);
  k_gemm2<<<dim3(16, DMODEL / 128, NE), 256, 0, stream>>>(act, Wd, slot_tok, offs, counts, y);
}

// Round 2
// 632.250 us; speedup vs baseline: 3.0978x; 3.0978x over previous
//
#include <hip/hip_runtime.h>
#include <hip/hip_bf16.h>
#include <cstdint>

// Problem constants (from reference)
#define TT     2048   // tokens
#define KSEL   6      // experts per token
#define DMODEL 2048   // model dim
#define DINTER 1408   // moe intermediate dim
#define NE     16     // routed experts
#define PMAX   (TT * KSEL)

typedef short bf16x8 __attribute__((ext_vector_type(8)));
typedef float f32x4 __attribute__((ext_vector_type(4)));
typedef unsigned short u16;
typedef u16 u16x8 __attribute__((ext_vector_type(8)));

__device__ __forceinline__ u16 f2bf(float f) {
  union { float f; unsigned u; } v; v.f = f;
  return (u16)((v.u + 0x7FFFu + ((v.u >> 16) & 1u)) >> 16);  // RNE
}

__device__ __forceinline__ void gl2lds16(const void* g, void* l) {
  __builtin_amdgcn_global_load_lds((const __attribute__((address_space(1))) void*)g,
                                   (__attribute__((address_space(3))) void*)l,
                                   16, 0, 0);
}

// gate_w[t,e] = sum_k weights[t,k]*(indices[t,k]==e); count routed (t,e) pairs
__global__ void k_gate(const float* __restrict__ w, const int* __restrict__ idx,
                       float* __restrict__ gate_w, int* __restrict__ counts) {
  int g = blockIdx.x * 256 + threadIdx.x;  // T*E threads
  int t = g >> 4, e = g & 15;
  const int* ip = idx + t * KSEL;
  const float* wp = w + t * KSEL;
  float s = 0.f;
#pragma unroll
  for (int k = 0; k < KSEL; ++k) s += (ip[k] == e) ? wp[k] : 0.f;
  gate_w[g] = s;
  if (s != 0.f) atomicAdd(counts + e, 1);
}

__global__ void k_scan(const int* __restrict__ counts, int* __restrict__ offs) {
  if (threadIdx.x == 0 && blockIdx.x == 0) {
    int r = 0;
#pragma unroll
    for (int e = 0; e < NE; ++e) { offs[e] = r; r += counts[e]; }
    offs[NE] = r;
  }
}

__global__ void k_fill(const float* __restrict__ gate_w, const int* __restrict__ offs,
                       int* __restrict__ cursor, int* __restrict__ slot_tok,
                       float* __restrict__ slot_gate) {
  int g = blockIdx.x * 256 + threadIdx.x;
  int t = g >> 4, e = g & 15;
  float s = gate_w[g];
  if (s != 0.f) {
    int p = atomicAdd(cursor + e, 1);
    int sl = offs[e] + p;
    slot_tok[sl] = t;
    slot_gate[sl] = s;
  }
}

// grid-strided fp32 -> bf16 cast, 8 elems/thread
__global__ void k_castw(const float* __restrict__ src, u16* __restrict__ dst, int n8) {
  int stride = gridDim.x * 256;
  for (int i = blockIdx.x * 256 + threadIdx.x; i < n8; i += stride) {
    const float4* p = (const float4*)src + (size_t)i * 2;
    float4 v0 = p[0], v1 = p[1];
    u16x8 o;
    o[0] = f2bf(v0.x); o[1] = f2bf(v0.y); o[2] = f2bf(v0.z); o[3] = f2bf(v0.w);
    o[4] = f2bf(v1.x); o[5] = f2bf(v1.y); o[6] = f2bf(v1.z); o[7] = f2bf(v1.w);
    *(u16x8*)(dst + (size_t)i * 8) = o;
  }
}

// GEMM1: act[slot, i] = silu(x@WgT)*(x@WuT)*gate, per expert token-group.
// Pure-bf16, all three tiles via global_load_lds width=16 (m97 structure).
// 128(M tokens) x 128(N inter) tile, BK=64, 4 waves each 64x64, dual acc (g,u).
__global__ __launch_bounds__(256, 2) void k_gemm1(
    const u16* __restrict__ xb, const u16* __restrict__ wgb, const u16* __restrict__ wub,
    const int* __restrict__ slot_tok, const float* __restrict__ slot_gate,
    const int* __restrict__ offs, const int* __restrict__ counts,
    u16* __restrict__ act) {
  // XCD-chunked swizzle: grid flat = 16(mt) x 11(it) x 16(e) = 2816 = 8*352.
  // New id b runs on XCD b%8; give each XCD a contiguous chunk of work ids so
  // m-tiles/i-tiles of one expert share an XCD L2.
  int b = blockIdx.x;
  int w = (b & 7) * 352 + (b >> 3);
  int mt = w & 15, rest = w >> 4;
  int it = rest % 11, e = rest / 11;

  int mcount = counts[e];
  if (mt * 128 >= mcount) return;
  int mrem = mcount - mt * 128; if (mrem > 128) mrem = 128;
  int slotBase = offs[e] + mt * 128;
  int iBase = it * 128;

  __shared__ u16 sA[128 * 64];
  __shared__ u16 sG[128 * 64];
  __shared__ u16 sU[128 * 64];
  __shared__ int tokLds[128];
  __shared__ float gateLds[128];

  int tid = threadIdx.x;
  if (tid < 128) {
    int rl = tid < mrem ? tid : 0;        // pad rows clamp to row 0 (valid addr)
    tokLds[tid] = slot_tok[slotBase + rl];
    gateLds[tid] = (tid < mrem) ? slot_gate[slotBase + rl] : 0.f;
  }
  __syncthreads();

  int wv = tid >> 6, lane = tid & 63;
  // staging: each tile = 16 chunks of 1KB (8 rows x 128B); wave wv owns chunks wv*4..wv*4+3
  // LDS dest = chunk base + lane*16 (HW rule); chunk row = c*8 + (lane>>3), col16B = lane&7
  const u16 *aSrc[4], *gSrc[4], *uSrc[4];
  u16 *aDst[4], *gDst[4], *uDst[4];
  const u16* gBase = wgb + ((size_t)e * DINTER + iBase) * DMODEL;
  const u16* uBase = wub + ((size_t)e * DINTER + iBase) * DMODEL;
#pragma unroll
  for (int i2 = 0; i2 < 4; ++i2) {
    int chunk = wv * 4 + i2;
    int row = chunk * 8 + (lane >> 3);
    int colOff = (lane & 7) * 8;
    aSrc[i2] = xb + (size_t)tokLds[row] * DMODEL + colOff;
    gSrc[i2] = gBase + (size_t)row * DMODEL + colOff;
    uSrc[i2] = uBase + (size_t)row * DMODEL + colOff;
    aDst[i2] = sA + chunk * 512;
    gDst[i2] = sG + chunk * 512;
    uDst[i2] = sU + chunk * 512;
  }

  f32x4 accg[4][4] = {};
  f32x4 accu[4][4] = {};
  int fr = lane & 15, fq = lane >> 4;
  int wr = (wv >> 1) * 64, wc = (wv & 1) * 64;

  for (int kb = 0; kb < DMODEL / 64; ++kb) {
    int kOff = kb * 64;
    __syncthreads();
#pragma unroll
    for (int i2 = 0; i2 < 4; ++i2) {
      gl2lds16(aSrc[i2] + kOff, aDst[i2]);
      gl2lds16(gSrc[i2] + kOff, gDst[i2]);
      gl2lds16(uSrc[i2] + kOff, uDst[i2]);
    }
    __syncthreads();
#pragma unroll
    for (int kf = 0; kf < 2; ++kf) {
      bf16x8 af[4], bg[4], bu[4];
#pragma unroll
      for (int mf = 0; mf < 4; ++mf)
        af[mf] = *(const bf16x8*)&sA[(wr + mf * 16 + fr) * 64 + kf * 32 + fq * 8];
#pragma unroll
      for (int nf = 0; nf < 4; ++nf) {
        bg[nf] = *(const bf16x8*)&sG[(wc + nf * 16 + fr) * 64 + kf * 32 + fq * 8];
        bu[nf] = *(const bf16x8*)&sU[(wc + nf * 16 + fr) * 64 + kf * 32 + fq * 8];
      }
#pragma unroll
      for (int mf = 0; mf < 4; ++mf)
#pragma unroll
        for (int nf = 0; nf < 4; ++nf) {
          accg[mf][nf] = __builtin_amdgcn_mfma_f32_16x16x32_bf16(af[mf], bg[nf], accg[mf][nf], 0, 0, 0);
          accu[mf][nf] = __builtin_amdgcn_mfma_f32_16x16x32_bf16(af[mf], bu[nf], accu[mf][nf], 0, 0, 0);
        }
    }
  }
  // epilogue: act = silu(g)*u*gate -> bf16  (D layout: col=lane&15, row=(lane>>4)*4+r)
#pragma unroll
  for (int mf = 0; mf < 4; ++mf)
#pragma unroll
    for (int nf = 0; nf < 4; ++nf)
#pragma unroll
      for (int r = 0; r < 4; ++r) {
        int row = wr + mf * 16 + fq * 4 + r;
        if (row < mrem) {
          float g = accg[mf][nf][r], u = accu[mf][nf][r];
          float a = g / (1.f + __expf(-g)) * u * gateLds[row];
          act[(size_t)(slotBase + row) * DINTER + iBase + wc + nf * 16 + fr] = f2bf(a);
        }
      }
}

// GEMM2: y[tok, d] += act[slot,:] @ Wd[e,d,:]  (atomic scatter, <=6 adds/elem)
__global__ __launch_bounds__(256, 4) void k_gemm2(
    const u16* __restrict__ act, const u16* __restrict__ wdb,
    const int* __restrict__ slot_tok, const int* __restrict__ offs,
    const int* __restrict__ counts, float* __restrict__ y) {
  // grid flat = 16(mt) x 16(dt) x 16(e) = 4096 = 8*512
  int b = blockIdx.x;
  int w = (b & 7) * 512 + (b >> 3);
  int mt = w & 15, rest = w >> 4;
  int dt = rest & 15, e = rest >> 4;

  int mcount = counts[e];
  if (mt * 128 >= mcount) return;
  int mrem = mcount - mt * 128; if (mrem > 128) mrem = 128;
  int slotBase = offs[e] + mt * 128;
  int dBase = dt * 128;

  __shared__ u16 sA[128 * 64];
  __shared__ u16 sB[128 * 64];
  __shared__ int tokLds[128];

  int tid = threadIdx.x;
  if (tid < 128) tokLds[tid] = slot_tok[slotBase + (tid < mrem ? tid : 0)];
  __syncthreads();

  int wv = tid >> 6, lane = tid & 63;
  const u16 *aSrc[4], *bSrc[4];
  u16 *aDst[4], *bDst[4];
  const u16* bBase = wdb + ((size_t)e * DMODEL + dBase) * DINTER;
#pragma unroll
  for (int i2 = 0; i2 < 4; ++i2) {
    int chunk = wv * 4 + i2;
    int row = chunk * 8 + (lane >> 3);
    int colOff = (lane & 7) * 8;
    aSrc[i2] = act + (size_t)(slotBase + row) * DINTER + colOff;  // act padded +128 rows
    bSrc[i2] = bBase + (size_t)row * DINTER + colOff;
    aDst[i2] = sA + chunk * 512;
    bDst[i2] = sB + chunk * 512;
  }

  f32x4 acc[4][4] = {};
  int fr = lane & 15, fq = lane >> 4;
  int wr = (wv >> 1) * 64, wc = (wv & 1) * 64;

  for (int kb = 0; kb < DINTER / 64; ++kb) {
    int kOff = kb * 64;
    __syncthreads();
#pragma unroll
    for (int i2 = 0; i2 < 4; ++i2) {
      gl2lds16(aSrc[i2] + kOff, aDst[i2]);
      gl2lds16(bSrc[i2] + kOff, bDst[i2]);
    }
    __syncthreads();
#pragma unroll
    for (int kf = 0; kf < 2; ++kf) {
      bf16x8 af[4], bb[4];
#pragma unroll
      for (int mf = 0; mf < 4; ++mf)
        af[mf] = *(const bf16x8*)&sA[(wr + mf * 16 + fr) * 64 + kf * 32 + fq * 8];
#pragma unroll
      for (int nf = 0; nf < 4; ++nf)
        bb[nf] = *(const bf16x8*)&sB[(wc + nf * 16 + fr) * 64 + kf * 32 + fq * 8];
#pragma unroll
      for (int mf = 0; mf < 4; ++mf)
#pragma unroll
        for (int nf = 0; nf < 4; ++nf)
          acc[mf][nf] = __builtin_amdgcn_mfma_f32_16x16x32_bf16(af[mf], bb[nf], acc[mf][nf], 0, 0, 0);
    }
  }
#pragma unroll
  for (int mf = 0; mf < 4; ++mf)
#pragma unroll
    for (int nf = 0; nf < 4; ++nf)
#pragma unroll
      for (int r = 0; r < 4; ++r) {
        int row = wr + mf * 16 + fq * 4 + r;
        if (row < mrem) {
          int t = tokLds[row];
          atomicAdd(y + (size_t)t * DMODEL + dBase + wc + nf * 16 + fr, acc[mf][nf][r]);
        }
      }
}

extern "C" void kernel_launch(void* const* d_in, const int* in_sizes, int n_in,
                              void* d_out, int out_size, void* d_ws, size_t ws_size,
                              hipStream_t stream) {
  const float* x       = (const float*)d_in[0];
  const float* weights = (const float*)d_in[1];
  const int*   indices = (const int*)d_in[2];
  const float* Wg      = (const float*)d_in[3];
  const float* Wu      = (const float*)d_in[4];
  const float* Wd      = (const float*)d_in[5];
  float* y = (float*)d_out;

  const size_t WELEM = (size_t)NE * DINTER * DMODEL;  // 46.1M elems per weight tensor

  char* ws = (char*)d_ws;
  size_t o = 0;
  float* gate_w = (float*)(ws + o); o += (size_t)TT * NE * 4;       // 131072
  size_t ctrlOff = o;
  int* counts = (int*)(ws + o);
  int* offs   = (int*)(ws + o + 64);
  int* cursor = (int*)(ws + o + 192);
  o += 256;
  int*   slot_tok  = (int*)(ws + o);   o += (size_t)PMAX * 4;
  float* slot_gate = (float*)(ws + o); o += (size_t)PMAX * 4;
  u16* xb  = (u16*)(ws + o); o += (size_t)TT * DMODEL * 2;
  u16* act = (u16*)(ws + o); o += (size_t)(PMAX + 128) * DINTER * 2; // +128 pad rows
  u16* wgb = (u16*)(ws + o); o += WELEM * 2;
  u16* wub = (u16*)(ws + o); o += WELEM * 2;
  u16* wdb = (u16*)(ws + o); o += WELEM * 2;   // total ~306 MB
  (void)ws_size; (void)in_sizes; (void)n_in;

  hipMemsetAsync(d_out, 0, (size_t)out_size * 4, stream);
  hipMemsetAsync(ws + ctrlOff, 0, 256, stream);

  k_gate<<<TT * NE / 256, 256, 0, stream>>>(weights, indices, gate_w, counts);
  k_scan<<<1, 64, 0, stream>>>(counts, offs);
  k_fill<<<TT * NE / 256, 256, 0, stream>>>(gate_w, offs, cursor, slot_tok, slot_gate);
  k_castw<<<(TT * DMODEL / 8) / 256, 256, 0, stream>>>(x, xb, TT * DMODEL / 8);
  k_castw<<<2048, 256, 0, stream>>>(Wg, wgb, (int)(WELEM / 8));
  k_castw<<<2048, 256, 0, stream>>>(Wu, wub, (int)(WELEM / 8));
  k_castw<<<2048, 256, 0, stream>>>(Wd, wdb, (int)(WELEM / 8));
  k_gemm1<<<2816, 256, 0, stream>>>(xb, wgb, wub, slot_tok, slot_gate, offs, counts, act);
  k_gemm2<<<4096, 256, 0, stream>>>(act, wdb, slot_tok, offs, counts, y);
}